// Round 11
// baseline (93.157 us; speedup 1.0000x reference)
//
#include <hip/hip_runtime.h>
#include <hip/hip_bf16.h>
#include <math.h>

#define VOCAB 2048
#define EMB 256
#define MAXLEN 8
#define NBATCH 16
#define LAT 16
#define NBLK 128
#define AGENT __HIP_MEMORY_SCOPE_AGENT

typedef unsigned short u16;
typedef unsigned int u32;
typedef unsigned long long u64;
using bf16x8 = __attribute__((ext_vector_type(8))) short;
using f32x4  = __attribute__((ext_vector_type(4))) float;

// token = argmax_j ( j/2048 <= v && v <= (j+1)/2048 ), 0 if none.
// cumsum of uniform softmax is exactly k/2048 in fp32; v*2048 is exact.
__device__ __forceinline__ int token_of(float v) {
    float u = v * 2048.0f;
    if (!(u >= 0.0f) || u > 2048.0f) return 0;   // v<0, v>1, or NaN
    int k = (int)ceilf(u) - 1;
    return k < 0 ? 0 : k;
}

__device__ __forceinline__ float sigmoidf_(float x) { return 1.0f / (1.0f + expf(-x)); }

__device__ __forceinline__ u16 to_bf16(float x) {
    __hip_bfloat16 hb = __float2bfloat16(x);   // RTNE
    return *reinterpret_cast<u16*>(&hb);
}

// Agent-scope (device-coherent-point) accessors: bypass the non-coherent
// per-XCD L2s for cross-block data. Relaxed: never emits wbl2/inv.
__device__ __forceinline__ void st_ag_f32(float* p, float v) {
    __hip_atomic_store(p, v, __ATOMIC_RELAXED, AGENT);
}
__device__ __forceinline__ float ld_ag_f32(const float* p) {
    return __hip_atomic_load(const_cast<float*>(p), __ATOMIC_RELAXED, AGENT);
}
__device__ __forceinline__ void st_ag_u32(u32* p, u32 v) {
    __hip_atomic_store(p, v, __ATOMIC_RELAXED, AGENT);
}
__device__ __forceinline__ u64 ld_ag_u64(const u64* p) {
    return __hip_atomic_load(const_cast<u64*>(p), __ATOMIC_RELAXED, AGENT);
}

// Grid barrier with NO cache maintenance: per-wave vmcnt drain (orders the
// agent stores) -> block barrier -> tid0 relaxed add + spin -> block barrier.
// All 128 blocks co-resident (128 <= 256 CUs).
__device__ __forceinline__ void gridbar(int* bar, int phase) {
    asm volatile("s_waitcnt vmcnt(0)" ::: "memory");
    __syncthreads();
    if (threadIdx.x == 0) {
        __hip_atomic_fetch_add(&bar[phase], 1, __ATOMIC_RELAXED, AGENT);
        while (__hip_atomic_load(&bar[phase], __ATOMIC_RELAXED, AGENT) < NBLK)
            __builtin_amdgcn_s_sleep(2);
    }
    __syncthreads();
}

// ---- K1: Wr -> BW pack. Fragment (l,i) = bf16(W[(k0*32+8*(l>>4)+i)*8192 +
// ntile*16 + (l&15)]); storage block-contiguous: st = (ntile&127)*4 + ntile>>7.
__global__ __launch_bounds__(256) void k_pack(const float* __restrict__ Wr,
                                              u16* __restrict__ BW) {
    int gidx = blockIdx.x * 256 + threadIdx.x;
    int l = gidx & 63;
    int k0 = (gidx >> 6) & 63;
    int ntile = gidx >> 12;
    const float* s = Wr + (size_t)(k0 * 32 + 8 * (l >> 4)) * 8192 + ntile * 16 + (l & 15);
    u16 o[8];
    #pragma unroll
    for (int i = 0; i < 8; ++i) o[i] = to_bf16(s[(size_t)i * 8192]);
    int st = (ntile & 127) * 4 + (ntile >> 7);
    *(uint4*)(BW + ((size_t)(st * 64 + k0) * 64 + l) * 8) = *(uint4*)o;
}

// ---- K2: Wk -> BWk pack (blocks 0..1023) + XA pack (1024..1039) + bar zero.
__global__ __launch_bounds__(256) void k_prep(
        const float* __restrict__ Wk, u16* __restrict__ BWk,
        const float* __restrict__ ip, const float* __restrict__ E,
        u16* __restrict__ XA, int* __restrict__ bar) {
    int bx = blockIdx.x;
    int tid = threadIdx.x;
    if (bx < 1024) {
        int gidx = bx * 256 + tid;
        int l = gidx & 63;
        int k0 = (gidx >> 6) & 7;
        int ntile = gidx >> 9;
        const float* s = Wk + (size_t)(k0 * 32 + 8 * (l >> 4)) * 8192 + ntile * 16 + (l & 15);
        u16 o[8];
        #pragma unroll
        for (int i = 0; i < 8; ++i) o[i] = to_bf16(s[(size_t)i * 8192]);
        int st = (ntile & 127) * 4 + (ntile >> 7);
        *(uint4*)(BWk + ((size_t)(st * 8 + k0) * 64 + l) * 8) = *(uint4*)o;
    } else if (bx < 1040) {
        int gidx = (bx - 1024) * 256 + tid;   // 0..4095
        int l = gidx & 63;
        int k0 = (gidx >> 6) & 7;
        int t = gidx >> 9;
        int b = l & 15;
        int tok = token_of(ip[b * LAT + t]);
        const float* s = E + (size_t)tok * EMB + k0 * 32 + 8 * (l >> 4);
        u16 o[8];
        #pragma unroll
        for (int i = 0; i < 8; ++i) o[i] = to_bf16(s[i]);
        *(uint4*)(XA + (size_t)gidx * 8) = *(uint4*)o;
    } else {
        if (tid < 16) bar[tid] = 0;
    }
}

// ---- K3: persistent sequence. 128 blocks x 1024 thr (16 waves).
// Block bid owns u-tile [bid*16, bid*16+16) for all 4 gates (st = bid*4+g).
// Phases: XZ(all t, into LDS)+step0 | bar0 | 7x(GEMM+update | bar t) | softmax.
// Cross-block data (hA, H) via agent-scope ops only; weights/LDS stay local.
__global__ __launch_bounds__(1024) void k_seq(
        const u16* __restrict__ BW, const u16* __restrict__ BWk,
        const u16* __restrict__ XA, const float* __restrict__ bv,
        const float* __restrict__ ip, u16* __restrict__ hA0,
        u16* __restrict__ hA1, float* __restrict__ H,
        float* __restrict__ out, int* __restrict__ bar) {
    int tid = threadIdx.x;
    int bid = blockIdx.x;        // 0..127
    int w = tid >> 6;            // 0..15
    int l = tid & 63;

    __shared__ float xzsh[8][4][256];   // 32 KB: xz for this block's u-tile
    __shared__ float zsh[16][256];      // 16 KB: per-step gate partials
    __shared__ float redm[16], reds[16];

    float h_reg = 0.0f, c_reg = 0.0f;   // persistent state (tid<256)
    int bb = tid >> 4;                  // batch (valid tid<256)
    int ul = tid & 15;
    int myu = bid * 16 + ul;            // owned u (valid tid<256)

    // ---- Phase XZ: wave (g = w>>2, tp = w&3) computes xz for t = 2tp, 2tp+1 ----
    {
        int g = w >> 2, tp = w & 3;
        int st = bid * 4 + g;
        const bf16x8* bp = (const bf16x8*)(BWk + ((size_t)(st * 8) * 64 + l) * 8);
        bf16x8 bw[8];
        #pragma unroll
        for (int s = 0; s < 8; ++s) bw[s] = bp[s * 64];
        float bias = bv[g * 2048 + bid * 16 + (l & 15)];
        #pragma unroll
        for (int q = 0; q < 2; ++q) {
            int t = tp * 2 + q;
            const bf16x8* ap = (const bf16x8*)(XA + ((size_t)(t * 8) * 64 + l) * 8);
            bf16x8 av[8];
            #pragma unroll
            for (int s = 0; s < 8; ++s) av[s] = ap[s * 64];
            f32x4 acc = {bias, bias, bias, bias};
            #pragma unroll
            for (int s = 0; s < 8; ++s)
                acc = __builtin_amdgcn_mfma_f32_16x16x32_bf16(av[s], bw[s], acc, 0, 0, 0);
            #pragma unroll
            for (int i = 0; i < 4; ++i)
                xzsh[t][g][(4 * (l >> 4) + i) * 16 + (l & 15)] = acc[i];
        }
    }
    __syncthreads();

    // ---- step0 (h=c=0) ----
    if (tid < 256) {
        float z0 = xzsh[0][0][tid], z2 = xzsh[0][2][tid], z3 = xzsh[0][3][tid];
        float cn = sigmoidf_(z0) * tanhf(z2);
        float hn = sigmoidf_(z3) * tanhf(cn);
        int tok = token_of(ip[bb * LAT + 0]);
        h_reg = tok != 0 ? hn : 0.0f;
        c_reg = tok != 0 ? cn : 0.0f;
        st_ag_f32(&H[bb * 2048 + myu], h_reg);
        u16 own = to_bf16(h_reg);
        int pair = __shfl_xor((int)own, 1);
        if (!(ul & 1)) {
            u32 val = (u32)own | ((u32)(u16)pair << 16);
            int k0 = myu >> 5, lg = (myu >> 3) & 3, i = myu & 7;
            st_ag_u32((u32*)hA1 + (((k0 * 64) + lg * 16 + bb) * 8 + i) / 2, val);
        }
    }
    gridbar(bar, 0);

    // ---- Steps 1..7: hoist B-fragments once (64 VGPR), reuse all steps ----
    int g = w >> 2, kq = w & 3;
    int st = bid * 4 + g;
    const bf16x8* bp = (const bf16x8*)(BW + (((size_t)(st * 64) + kq * 16) * 64 + l) * 8);
    bf16x8 br[16];
    #pragma unroll
    for (int i = 0; i < 16; ++i) br[i] = bp[i * 64];

    for (int t = 1; t < MAXLEN; ++t) {
        const u16* hAin = (t & 1) ? hA1 : hA0;
        u16* hAout = (t & 1) ? hA0 : hA1;
        const u64* aq = (const u64*)hAin + ((size_t)(kq * 16) * 64 + l) * 2;

        union { u64 q[2]; bf16x8 v; } ar[8];
        #pragma unroll
        for (int i = 0; i < 8; ++i) {
            ar[i].q[0] = ld_ag_u64(aq + i * 128);
            ar[i].q[1] = ld_ag_u64(aq + i * 128 + 1);
        }
        f32x4 acc = {0.f, 0.f, 0.f, 0.f};
        #pragma unroll
        for (int s = 0; s < 16; ++s) {
            bf16x8 a = ar[s & 7].v;
            if (s + 8 < 16) {
                ar[s & 7].q[0] = ld_ag_u64(aq + (s + 8) * 128);
                ar[s & 7].q[1] = ld_ag_u64(aq + (s + 8) * 128 + 1);
            }
            acc = __builtin_amdgcn_mfma_f32_16x16x32_bf16(a, br[s], acc, 0, 0, 0);
        }
        #pragma unroll
        for (int i = 0; i < 4; ++i)
            zsh[w][(4 * (l >> 4) + i) * 16 + (l & 15)] = acc[i];
        __syncthreads();

        if (tid < 256) {
            float z[4];
            #pragma unroll
            for (int gg = 0; gg < 4; ++gg)
                z[gg] = zsh[gg * 4 + 0][tid] + zsh[gg * 4 + 1][tid]
                      + zsh[gg * 4 + 2][tid] + zsh[gg * 4 + 3][tid]
                      + xzsh[t][gg][tid];
            float cn = sigmoidf_(z[1]) * c_reg + sigmoidf_(z[0]) * tanhf(z[2]);
            float hn = sigmoidf_(z[3]) * tanhf(cn);
            int tok = token_of(ip[bb * LAT + t]);
            h_reg = tok != 0 ? hn : h_reg;
            c_reg = tok != 0 ? cn : c_reg;
            st_ag_f32(&H[(t * 16 + bb) * 2048 + myu], h_reg);
            u16 own = to_bf16(h_reg);
            int pair = __shfl_xor((int)own, 1);
            if (!(ul & 1)) {
                u32 val = (u32)own | ((u32)(u16)pair << 16);
                int k0 = myu >> 5, lg = (myu >> 3) & 3, i = myu & 7;
                st_ag_u32((u32*)hAout + (((k0 * 64) + lg * 16 + bb) * 8 + i) / 2, val);
            }
        }
        gridbar(bar, t);
    }

    // ---- Softmax: block bid handles row r = bid (= t*16 + b) ----
    {
        int r = bid;
        int t = r >> 4, b = r & 15;
        const float* hr = H + (size_t)r * VOCAB;
        float v0 = ld_ag_f32(hr + tid);
        float v1 = ld_ag_f32(hr + tid + 1024);
        float m = fmaxf(v0, v1);
        #pragma unroll
        for (int off = 32; off; off >>= 1) m = fmaxf(m, __shfl_down(m, off));
        if (l == 0) redm[w] = m;
        __syncthreads();
        m = redm[0];
        #pragma unroll
        for (int i = 1; i < 16; ++i) m = fmaxf(m, redm[i]);
        float e0 = expf(v0 - m), e1 = expf(v1 - m);
        float s = e0 + e1;
        #pragma unroll
        for (int off = 32; off; off >>= 1) s += __shfl_down(s, off);
        if (l == 0) reds[w] = s;
        __syncthreads();
        s = reds[0];
        #pragma unroll
        for (int i = 1; i < 16; ++i) s += reds[i];
        float* o = out + ((size_t)b * MAXLEN + t) * VOCAB;
        o[tid] = e0 / s;
        o[tid + 1024] = e1 / s;
    }
}

extern "C" void kernel_launch(void* const* d_in, const int* in_sizes, int n_in,
                              void* d_out, int out_size, void* d_ws, size_t ws_size,
                              hipStream_t stream) {
    const float* ip = (const float*)d_in[0];   // (16,16)
    const float* E  = (const float*)d_in[1];   // (2048,256)
    const float* Wk = (const float*)d_in[2];   // (256,8192)
    const float* Wr = (const float*)d_in[3];   // (2048,8192)
    const float* bv = (const float*)d_in[4];   // (8192,)

    char* w = (char*)d_ws;
    float* H   = (float*)w;  w += (size_t)262144 * 4;                  // 1 MB
    u16* XA  = (u16*)w;      w += (size_t)32768 * 2;                   // 64 KB
    u16* hA0 = (u16*)w;      w += (size_t)32768 * 2;
    u16* hA1 = (u16*)w;      w += (size_t)32768 * 2;
    u16* BWk = (u16*)w;      w += (size_t)2097152 * 2;                 // 4 MB
    u16* BW  = (u16*)w;      w += (size_t)16777216 * 2;                // 32 MB
    int* bar = (int*)w;      w += 64 * 4;

    k_pack<<<8192, 256, 0, stream>>>(Wr, BW);
    k_prep<<<1041, 256, 0, stream>>>(Wk, BWk, ip, E, XA, bar);
    k_seq<<<NBLK, 1024, 0, stream>>>(BW, BWk, XA, bv, ip, hA0, hA1,
                                     H, (float*)d_out, bar);
}